// Round 18
// baseline (68.973 us; speedup 1.0000x reference)
//
#include <hip/hip_runtime.h>
#include <hip/hip_bf16.h>
#include <stdint.h>

typedef float f32x4 __attribute__((ext_vector_type(4)));
typedef __bf16 bf16x8 __attribute__((ext_vector_type(8)));
typedef unsigned short ushort8 __attribute__((ext_vector_type(8)));

#define N_TOK 128
#define OUT_F 8192
#define IN_F  8192
#define RANK  32

#define KSPLIT 8                // main-gemm k-split
#define KB    (IN_F / KSPLIT)   // 1024 codes per block
#define BK    64
#define NSTEP (KB / BK)         // 16
#define WSTRIDE 16              // ints per step per W row (BK/4)
#define LKC   4                 // lora-t k-chunks

// workspace layout (bytes)
#define XB_OFF 0
#define TB_OFF ((size_t)N_TOK * IN_F * 2)                      // 2 MiB fragment-ordered bf16 x
// tB: LKC * 128 * 32 f32 = 64 KiB

__device__ __forceinline__ unsigned short bf16r(float f) {
    uint32_t u = __float_as_uint(f);
    return (unsigned short)((u + 0x7FFFu + ((u >> 16) & 1u)) >> 16);
}

__device__ __forceinline__ int swz(int row, int col) { return col ^ ((row & 7) << 3); }

// ---------------- kernel A: x fp32 -> bf16 in MFMA-fragment record order ----------------
// record rec = (sblk*2 + kk)*8 + ar16  (1 KiB each: 64 lanes x 16 B).
// lane l holds X[ar16*16 + (l&15)][sblk*64 + kk*32 + (l>>4)*8 .. +8].
__global__ __launch_bounds__(256) void cvt_x(const float* __restrict__ x,
                                             unsigned short* __restrict__ xt) {
    size_t f = (size_t)blockIdx.x * 256 + threadIdx.x;  // 0..131071 (16-B chunks)
    int lane = (int)(f & 63);
    int rec  = (int)(f >> 6);          // 0..2047
    int ar16 = rec & 7;
    int kk   = (rec >> 3) & 1;
    int sblk = rec >> 4;               // 0..127
    int row = ar16 * 16 + (lane & 15);
    int k   = sblk * 64 + kk * 32 + (lane >> 4) * 8;
    const float4* sp = (const float4*)(x + (size_t)row * IN_F + k);
    float4 a = sp[0], b = sp[1];
    ushort8 o;
    o[0] = bf16r(a.x); o[1] = bf16r(a.y); o[2] = bf16r(a.z); o[3] = bf16r(a.w);
    o[4] = bf16r(b.x); o[5] = bf16r(b.y); o[6] = bf16r(b.z); o[7] = bf16r(b.w);
    *(ushort8*)(xt + f * 8) = o;
}

// ---------------- kernel B: t-partials = x @ lora_B^T, coalesced ----------------
__global__ __launch_bounds__(256) void lora_t(const float* __restrict__ x,
                                              const float* __restrict__ lb,
                                              float* __restrict__ tB) {
    __shared__ float ts[256][33];
    __shared__ float ps[8][32];
    const int m = blockIdx.x >> 2, kc = blockIdx.x & 3;
    const int tid = threadIdx.x;
    const int c0 = kc * 2048 + tid * 8;
    float4 xv0 = *(const float4*)(x + (size_t)m * IN_F + c0);
    float4 xv1 = *(const float4*)(x + (size_t)m * IN_F + c0 + 4);
#pragma unroll
    for (int r = 0; r < RANK; ++r) {
        const float4* bp = (const float4*)(lb + (size_t)r * IN_F + c0);
        float4 b0 = bp[0], b1 = bp[1];
        float s = xv0.x * b0.x + xv0.y * b0.y + xv0.z * b0.z + xv0.w * b0.w +
                  xv1.x * b1.x + xv1.y * b1.y + xv1.z * b1.z + xv1.w * b1.w;
        ts[tid][r] = s;
    }
    __syncthreads();
    {
        int g = tid >> 5, r = tid & 31;
        float s = 0.f;
        for (int j = 0; j < 32; ++j) s += ts[g * 32 + j][r];
        ps[g][r] = s;
    }
    __syncthreads();
    if (tid < 32) {
        float s = 0.f;
#pragma unroll
        for (int g = 0; g < 8; ++g) s += ps[g][tid];
        tB[(kc * N_TOK + m) * RANK + tid] = s;
    }
}

// ---------------- kernel B2: out = bias + t @ lora_A^T (base for atomic accumulation) ----
// grid = 16 nb * 32 mg = 512 blocks; thread: 2 consecutive n, 4 m's
__global__ __launch_bounds__(256) void lora_out(const float* __restrict__ tB,
                                                const float* __restrict__ lora_A,
                                                const float* __restrict__ bias,
                                                float* __restrict__ out) {
    __shared__ float ts[4][RANK];
    int nb = blockIdx.x & 15, mg = blockIdx.x >> 4;
    int tid = threadIdx.x;
    int m0 = mg * 4;
    if (tid < 128) {
        int i = tid >> 5, r = tid & 31;
        float s = 0.f;
#pragma unroll
        for (int c = 0; c < LKC; ++c) s += tB[(c * N_TOK + m0 + i) * RANK + r];
        ts[i][r] = s;
    }
    __syncthreads();
    int n = nb * 512 + tid * 2;
    float bs0 = bias[n], bs1 = bias[n + 1];
    float4 a0[8], a1[8];
    const float4* ap0 = (const float4*)(lora_A + (size_t)n * RANK);
    const float4* ap1 = (const float4*)(lora_A + (size_t)(n + 1) * RANK);
#pragma unroll
    for (int q = 0; q < 8; ++q) { a0[q] = ap0[q]; a1[q] = ap1[q]; }
#pragma unroll
    for (int i = 0; i < 4; ++i) {
        int m = m0 + i;
        float l0 = 0.f, l1 = 0.f;
#pragma unroll
        for (int q = 0; q < 8; ++q) {
            float4 tv = *(const float4*)&ts[i][q * 4];
            l0 = fmaf(tv.x, a0[q].x, l0); l0 = fmaf(tv.y, a0[q].y, l0);
            l0 = fmaf(tv.z, a0[q].z, l0); l0 = fmaf(tv.w, a0[q].w, l0);
            l1 = fmaf(tv.x, a1[q].x, l1); l1 = fmaf(tv.y, a1[q].y, l1);
            l1 = fmaf(tv.z, a1[q].z, l1); l1 = fmaf(tv.w, a1[q].w, l1);
        }
        out[(size_t)m * OUT_F + n]     = l0 + bs0;
        out[(size_t)m * OUT_F + n + 1] = l1 + bs1;
    }
}

// ---------------- decode: 16 ternary codes (4 widened ints) -> 8 dwords of bf16 pairs ----------------
__device__ __forceinline__ void decodeW(int4 v, uint32_t d[8]) {
    uint32_t p = (uint32_t)v.x | ((uint32_t)v.y << 8) |
                 ((uint32_t)v.z << 16) | ((uint32_t)v.w << 24);
    const uint32_t HI = 0x403F00BFu;
    const uint32_t LO = 0x00800080u;
#pragma unroll
    for (int j = 0; j < 8; ++j) {
        uint32_t c0 = (p >> (4 * j)) & 3u;
        uint32_t c1 = (p >> (4 * j + 2)) & 3u;
        uint32_t t = c0 | (c1 << 16);
        uint32_t sel = (t | (t << 8)) + 0x04000400u;
        d[j] = __builtin_amdgcn_perm(HI, LO, sel);
    }
}

// ---------------- kernel C: ternary GEMM — dbuf ww, ONE barrier/step, ATOMIC epilogue ----
// A from L2 fragment records (JIT per kk); W coop-staged coalesced, decoded 1-ahead,
// packed loads 2-ahead; barriers drain ONLY lgkmcnt. Epilogue: out += acc*scale via
// hardware f32 atomics (no partials buffer, no reduce kernel).
// grid = 64 n-tiles * KSPLIT(8) = 512 blocks, 256 threads (4 waves, 2x2 of 64x64).
__global__ __launch_bounds__(256) void ternary_gemm(const unsigned short* __restrict__ xt,
                                                    const int* __restrict__ wp,
                                                    const float* __restrict__ scale,
                                                    float* __restrict__ out) {
    __shared__ unsigned short ww[2][128][64];  // 2 x 16 KiB, XOR-swizzled
    const int tid = threadIdx.x;
    const int nb = blockIdx.x >> 3;
    const int ks = blockIdx.x & 7;
    const int n0 = nb * 128;
    const int lane = tid & 63;
    const int wid = tid >> 6;
    const int wr = wid >> 1, wc = wid & 1;

    const int srow = tid >> 2;
    const int xcol = (tid & 3) * 16;
    const int* pg0 = wp + (size_t)(n0 + srow) * (IN_F / 4) + ks * (KB / 4) + (tid & 3) * 4;
    const int* pg1 = pg0 + (size_t)64 * (IN_F / 4);

    const int arow = lane & 15;
    const int kgrp = (lane >> 4) * 8;
    const int wc0 = swz(srow, xcol), wc1 = swz(srow, xcol + 8);

    // A record base: rec = (ks*NSTEP + s)*16 + kk*8 + ar16; 512 ushorts each
    const unsigned short* abase = xt + ((size_t)(ks * NSTEP) * 16) * 512 + lane * 8;
#define LDA(s_, kk_, ar_) \
    (*(const bf16x8*)(abase + ((size_t)((s_)*16 + (kk_)*8 + (wr * 4 + (ar_)))) * 512))

    f32x4 acc[4][4];
#pragma unroll
    for (int i = 0; i < 4; ++i)
#pragma unroll
        for (int j = 0; j < 4; ++j) acc[i][j] = (f32x4){0.f, 0.f, 0.f, 0.f};

    int4 wP[2][2];  // [parity][row-half] packed W ring; slot p holds next step of parity p

    // ---------- prologue: W(0),W(1) -> regs; decode W(0) -> ww[0]; W(2) -> slot0 ----------
    wP[0][0] = *(const int4*)(pg0);
    wP[0][1] = *(const int4*)(pg1);
    wP[1][0] = *(const int4*)(pg0 + WSTRIDE);
    wP[1][1] = *(const int4*)(pg1 + WSTRIDE);
    {
        uint32_t d0[8], d1[8];
        decodeW(wP[0][0], d0);
        decodeW(wP[0][1], d1);
        *(uint4*)&ww[0][srow][wc0]      = make_uint4(d0[0], d0[1], d0[2], d0[3]);
        *(uint4*)&ww[0][srow][wc1]      = make_uint4(d0[4], d0[5], d0[6], d0[7]);
        *(uint4*)&ww[0][srow + 64][wc0] = make_uint4(d1[0], d1[1], d1[2], d1[3]);
        *(uint4*)&ww[0][srow + 64][wc1] = make_uint4(d1[4], d1[5], d1[6], d1[7]);
    }
    wP[0][0] = *(const int4*)(pg0 + 2 * WSTRIDE);
    wP[0][1] = *(const int4*)(pg1 + 2 * WSTRIDE);
    __builtin_amdgcn_sched_barrier(0);
    asm volatile("s_waitcnt lgkmcnt(0)" ::: "memory");
    __builtin_amdgcn_s_barrier();
    __builtin_amdgcn_sched_barrier(0);

#pragma unroll
    for (int s = 0; s < NSTEP; ++s) {
        const int cur = s & 1, nxt = cur ^ 1;
        // MFMA on ww[cur]; A JIT per kk (L2-resident records, ride everything)
#pragma unroll
        for (int kk = 0; kk < 2; ++kk) {
            bf16x8 aK[4], bfr[4];
#pragma unroll
            for (int ar = 0; ar < 4; ++ar) aK[ar] = LDA(s, kk, ar);
#pragma unroll
            for (int br = 0; br < 4; ++br) {
                int row = wc * 64 + br * 16 + arow;
                bfr[br] = *(const bf16x8*)&ww[cur][row][swz(row, kk * 32 + kgrp)];
            }
#pragma unroll
            for (int ar = 0; ar < 4; ++ar)
#pragma unroll
                for (int br = 0; br < 4; ++br)
                    acc[ar][br] = __builtin_amdgcn_mfma_f32_16x16x32_bf16(
                        aK[ar], bfr[br], acc[ar][br], 0, 0, 0);
        }
        if (s + 1 < NSTEP) {
            // decode W(s+1) (loaded 2 steps ago) -> ww[nxt]
            uint32_t d0[8], d1[8];
            decodeW(wP[nxt][0], d0);
            decodeW(wP[nxt][1], d1);
            *(uint4*)&ww[nxt][srow][wc0]      = make_uint4(d0[0], d0[1], d0[2], d0[3]);
            *(uint4*)&ww[nxt][srow][wc1]      = make_uint4(d0[4], d0[5], d0[6], d0[7]);
            *(uint4*)&ww[nxt][srow + 64][wc0] = make_uint4(d1[0], d1[1], d1[2], d1[3]);
            *(uint4*)&ww[nxt][srow + 64][wc1] = make_uint4(d1[4], d1[5], d1[6], d1[7]);
            // refill freed slot with W(s+3) (2-step cover; rides across barriers)
            if (s + 3 < NSTEP) {
                wP[nxt][0] = *(const int4*)(pg0 + (s + 3) * WSTRIDE);
                wP[nxt][1] = *(const int4*)(pg1 + (s + 3) * WSTRIDE);
            }
            // single barrier: my reads of ww[cur] and writes of ww[nxt] both done
            __builtin_amdgcn_sched_barrier(0);
            asm volatile("s_waitcnt lgkmcnt(0)" ::: "memory");
            __builtin_amdgcn_s_barrier();
            __builtin_amdgcn_sched_barrier(0);
        }
    }
#undef LDA

    // epilogue: fold scale, hardware-atomic accumulate into out
    const int mrow = (lane >> 4) * 4;
#pragma unroll
    for (int br = 0; br < 4; ++br) {
        int n = n0 + wc * 64 + br * 16 + arow;
        float sc = scale[n];
#pragma unroll
        for (int ar = 0; ar < 4; ++ar) {
            int m = wr * 64 + ar * 16 + mrow;
            float* pp = out + (size_t)m * OUT_F + n;
#pragma unroll
            for (int j = 0; j < 4; ++j)
                unsafeAtomicAdd(pp + (size_t)j * OUT_F, acc[ar][br][j] * sc);
        }
    }
}

extern "C" void kernel_launch(void* const* d_in, const int* in_sizes, int n_in,
                              void* d_out, int out_size, void* d_ws, size_t ws_size,
                              hipStream_t stream) {
    const float* x      = (const float*)d_in[0];
    const int*   wp     = (const int*)d_in[1];   // uint8 input -> int32 on device
    const float* scale  = (const float*)d_in[2];
    const float* lora_A = (const float*)d_in[3];
    const float* lora_B = (const float*)d_in[4];
    const float* bias   = (const float*)d_in[5];
    float* out = (float*)d_out;

    char* ws = (char*)d_ws;
    unsigned short* xt = (unsigned short*)(ws + XB_OFF);
    float* tB = (float*)(ws + TB_OFF);

    cvt_x<<<512, 256, 0, stream>>>(x, xt);
    lora_t<<<N_TOK * LKC, 256, 0, stream>>>(x, lora_B, tB);
    lora_out<<<16 * 32, 256, 0, stream>>>(tB, lora_A, bias, out);
    ternary_gemm<<<(OUT_F / 128) * KSPLIT, 256, 0, stream>>>(xt, wp, scale, out);
}

// Round 19
// 62.565 us; speedup vs baseline: 1.1024x; 1.1024x over previous
//
#include <hip/hip_runtime.h>
#include <hip/hip_bf16.h>
#include <stdint.h>

typedef float f32x4 __attribute__((ext_vector_type(4)));
typedef __bf16 bf16x8 __attribute__((ext_vector_type(8)));
typedef unsigned short ushort8 __attribute__((ext_vector_type(8)));
typedef uint32_t u32x4 __attribute__((ext_vector_type(4)));

#define N_TOK 128
#define OUT_F 8192
#define IN_F  8192
#define RANK  32

#define KSPLIT 8                // main-gemm k-split
#define KB    (IN_F / KSPLIT)   // 1024 codes per block
#define NSTEP (KB / 64)         // 16 K64 steps
#define LKC   4                 // lora-t k-chunks

// workspace layout (bytes)
#define XB_OFF 0
#define TB_OFF ((size_t)N_TOK * IN_F * 2)                      // 2 MiB fragment-ordered bf16 x
#define PO_OFF (TB_OFF + (size_t)LKC * N_TOK * RANK * 4)       // + 64 KiB t-partials
// pO: KSPLIT * 128 * 8192 bf16 = 16 MiB

__device__ __forceinline__ unsigned short bf16r(float f) {
    uint32_t u = __float_as_uint(f);
    return (unsigned short)((u + 0x7FFFu + ((u >> 16) & 1u)) >> 16);
}

// ---------------- kernel A: x fp32 -> bf16, fragment records, PERMUTED k-order ----------
// record rec = (sblk*2 + kk)*8 + ar16  (1 KiB: 64 lanes x 16 B).
// lane l (arow=l&15, kq=l>>4) holds X[ar16*16+arow][sblk*64 + kq*16 + kk*8 + e], e=0..7.
// phys_k(kq,kk,e) = kq*16 + kk*8 + e  — matches the B-side int4-per-lane split, so the
// MFMA contraction sums the same physical k on both operands.
__global__ __launch_bounds__(256) void cvt_x(const float* __restrict__ x,
                                             unsigned short* __restrict__ xt) {
    size_t f = (size_t)blockIdx.x * 256 + threadIdx.x;  // 0..131071 (16-B chunks)
    int lane = (int)(f & 63);
    int rec  = (int)(f >> 6);          // 0..2047
    int ar16 = rec & 7;
    int kk   = (rec >> 3) & 1;
    int sblk = rec >> 4;               // 0..127
    int row = ar16 * 16 + (lane & 15);
    int k   = sblk * 64 + (lane >> 4) * 16 + kk * 8;
    const float4* sp = (const float4*)(x + (size_t)row * IN_F + k);
    float4 a = sp[0], b = sp[1];
    ushort8 o;
    o[0] = bf16r(a.x); o[1] = bf16r(a.y); o[2] = bf16r(a.z); o[3] = bf16r(a.w);
    o[4] = bf16r(b.x); o[5] = bf16r(b.y); o[6] = bf16r(b.z); o[7] = bf16r(b.w);
    *(ushort8*)(xt + f * 8) = o;
}

// ---------------- kernel B: t-partials = x @ lora_B^T, coalesced ----------------
__global__ __launch_bounds__(256) void lora_t(const float* __restrict__ x,
                                              const float* __restrict__ lb,
                                              float* __restrict__ tB) {
    __shared__ float ts[256][33];
    __shared__ float ps[8][32];
    const int m = blockIdx.x >> 2, kc = blockIdx.x & 3;
    const int tid = threadIdx.x;
    const int c0 = kc * 2048 + tid * 8;
    float4 xv0 = *(const float4*)(x + (size_t)m * IN_F + c0);
    float4 xv1 = *(const float4*)(x + (size_t)m * IN_F + c0 + 4);
#pragma unroll
    for (int r = 0; r < RANK; ++r) {
        const float4* bp = (const float4*)(lb + (size_t)r * IN_F + c0);
        float4 b0 = bp[0], b1 = bp[1];
        float s = xv0.x * b0.x + xv0.y * b0.y + xv0.z * b0.z + xv0.w * b0.w +
                  xv1.x * b1.x + xv1.y * b1.y + xv1.z * b1.z + xv1.w * b1.w;
        ts[tid][r] = s;
    }
    __syncthreads();
    {
        int g = tid >> 5, r = tid & 31;
        float s = 0.f;
        for (int j = 0; j < 32; ++j) s += ts[g * 32 + j][r];
        ps[g][r] = s;
    }
    __syncthreads();
    if (tid < 32) {
        float s = 0.f;
#pragma unroll
        for (int g = 0; g < 8; ++g) s += ps[g][tid];
        tB[(kc * N_TOK + m) * RANK + tid] = s;
    }
}

// ---------------- decode: 8 ternary codes (2 widened ints) -> bf16x8 B-fragment ----------------
__device__ __forceinline__ bf16x8 decode8(int vx, int vy) {
    uint32_t p = (uint32_t)(vx & 0xFF) | (((uint32_t)(vy & 0xFF)) << 8);
    const uint32_t HI = 0x403F00BFu;  // {-1:BF80, 0:0000, +1:3F80}
    const uint32_t LO = 0x00800080u;
    u32x4 d;
#pragma unroll
    for (int j = 0; j < 4; ++j) {
        uint32_t c0 = (p >> (4 * j)) & 3u;
        uint32_t c1 = (p >> (4 * j + 2)) & 3u;
        uint32_t t = c0 | (c1 << 16);
        uint32_t sel = (t | (t << 8)) + 0x04000400u;
        d[j] = __builtin_amdgcn_perm(HI, LO, sel);
    }
    return __builtin_bit_cast(bf16x8, d);
}

// ---------------- kernel C: ternary GEMM — 1-wave blocks, ZERO barriers, ZERO LDS ------
// Wave tile 64(M) x 32(N). A from L2 fragment records (16-B/lane coalesced, permuted-k).
// W: per lane ONE int4 per (step,br) = 16 contiguous codes (64-B segments per 4-lane
// row group) covering BOTH kk fragments; prefetched 2 steps ahead in registers.
// grid = 2 mh * 256 n-tiles * KSPLIT(8) = 4096 blocks x 64 threads -> 16 waves/CU,
// all free-running (no inter-wave dependency of any kind).
__global__ __launch_bounds__(64) void ternary_gemm(const unsigned short* __restrict__ xt,
                                                   const int* __restrict__ wp,
                                                   unsigned short* __restrict__ pO) {
    const int b = blockIdx.x;
    const int ks = b & 7;
    const int t = b >> 3;            // 0..511
    const int mh = t & 1;            // M-half (rows mh*64..+64)
    const int n0 = (t >> 1) * 32;    // 0..255 n-tiles of 32
    const int lane = threadIdx.x;
    const int arow = lane & 15;
    const int kq = lane >> 4;        // 0..3

    // A record base: rec = (ks*NSTEP + s)*16 + kk*8 + (mh*4 + ar); 512 ushorts each
    const unsigned short* abase = xt + ((size_t)(ks * NSTEP) * 16) * 512 + lane * 8;
#define LDA(s_, kk_, ar_) \
    (*(const bf16x8*)(abase + ((size_t)((s_)*16 + (kk_)*8 + (mh * 4 + (ar_)))) * 512))

    // W: lane (kq,arow), frag-row-group br: row = n0 + br*16 + arow,
    // int4 at ints [ks*256 + s*16 + kq*4, +4) = codes [phys_k 0..16) of step s slot kq.
    const int* wbase = wp + (size_t)(n0 + arow) * (IN_F / 4) + ks * (KB / 4) + kq * 4;
#define LDW(s_, br_) (*(const int4*)(wbase + (size_t)(br_) * 16 * (IN_F / 4) + (s_) * 16))

    f32x4 acc[4][2];  // [ar][br]
#pragma unroll
    for (int i = 0; i < 4; ++i) { acc[i][0] = (f32x4){0,0,0,0}; acc[i][1] = (f32x4){0,0,0,0}; }

    int4 wA[2], wB[2];  // step-parity ping-pong, 2-step prefetch depth
    wA[0] = LDW(0, 0); wA[1] = LDW(0, 1);
    wB[0] = LDW(1, 0); wB[1] = LDW(1, 1);

#pragma unroll
    for (int s = 0; s < NSTEP; ++s) {
        int4* wcur = (s & 1) ? wB : wA;
#pragma unroll
        for (int kk = 0; kk < 2; ++kk) {
            bf16x8 aK[4];
#pragma unroll
            for (int ar = 0; ar < 4; ++ar) aK[ar] = LDA(s, kk, ar);
#pragma unroll
            for (int br = 0; br < 2; ++br) {
                bf16x8 bf = kk ? decode8(wcur[br].z, wcur[br].w)
                               : decode8(wcur[br].x, wcur[br].y);
#pragma unroll
                for (int ar = 0; ar < 4; ++ar)
                    acc[ar][br] = __builtin_amdgcn_mfma_f32_16x16x32_bf16(
                        aK[ar], bf, acc[ar][br], 0, 0, 0);
            }
        }
        if (s + 2 < NSTEP) {  // refill freed parity slot; ~2-step latency cover
            wcur[0] = LDW(s + 2, 0);
            wcur[1] = LDW(s + 2, 1);
        }
    }
#undef LDA
#undef LDW

    // epilogue: bf16 partial store.  C layout: col=lane&15, row=(lane>>4)*4+j.
    unsigned short* po = pO + ((size_t)ks << 20);
#pragma unroll
    for (int ar = 0; ar < 4; ++ar) {
#pragma unroll
        for (int br = 0; br < 2; ++br) {
            int m = mh * 64 + ar * 16 + kq * 4;
            int n = n0 + br * 16 + arow;
            unsigned short* pp = po + (size_t)m * OUT_F + n;
#pragma unroll
            for (int j = 0; j < 4; ++j) pp[(size_t)j * OUT_F] = bf16r(acc[ar][br][j]);
        }
    }
}

// ---------------- kernel D: reduce bf16 partials + scale + lora + bias ----------------
// grid = 16 nb * 32 mg = 512 blocks; thread: 2 consecutive n, 4 m's
__global__ __launch_bounds__(256) void reduce_out(const unsigned short* __restrict__ pO,
                                                  const float* __restrict__ tB,
                                                  const float* __restrict__ scale,
                                                  const float* __restrict__ lora_A,
                                                  const float* __restrict__ bias,
                                                  float* __restrict__ out) {
    __shared__ float ts[4][RANK];
    int nb = blockIdx.x & 15, mg = blockIdx.x >> 4;
    int tid = threadIdx.x;
    int m0 = mg * 4;
    if (tid < 128) {
        int i = tid >> 5, r = tid & 31;
        float s = 0.f;
#pragma unroll
        for (int c = 0; c < LKC; ++c) s += tB[(c * N_TOK + m0 + i) * RANK + r];
        ts[i][r] = s;
    }
    __syncthreads();
    int n = nb * 512 + tid * 2;
    float sc0 = scale[n], sc1 = scale[n + 1];
    float bs0 = bias[n], bs1 = bias[n + 1];
    float4 a0[8], a1[8];
    const float4* ap0 = (const float4*)(lora_A + (size_t)n * RANK);
    const float4* ap1 = (const float4*)(lora_A + (size_t)(n + 1) * RANK);
#pragma unroll
    for (int q = 0; q < 8; ++q) { a0[q] = ap0[q]; a1[q] = ap1[q]; }
#pragma unroll
    for (int i = 0; i < 4; ++i) {
        int m = m0 + i;
        const unsigned short* pp = pO + (size_t)m * OUT_F + n;
        float s0 = 0.f, s1 = 0.f;
#pragma unroll
        for (int c = 0; c < KSPLIT; ++c) {
            uint32_t u = *(const uint32_t*)(pp + ((size_t)c << 20));
            s0 += __uint_as_float(u << 16);
            s1 += __uint_as_float(u & 0xFFFF0000u);
        }
        float l0 = 0.f, l1 = 0.f;
#pragma unroll
        for (int q = 0; q < 8; ++q) {
            float4 tv = *(const float4*)&ts[i][q * 4];
            l0 = fmaf(tv.x, a0[q].x, l0); l0 = fmaf(tv.y, a0[q].y, l0);
            l0 = fmaf(tv.z, a0[q].z, l0); l0 = fmaf(tv.w, a0[q].w, l0);
            l1 = fmaf(tv.x, a1[q].x, l1); l1 = fmaf(tv.y, a1[q].y, l1);
            l1 = fmaf(tv.z, a1[q].z, l1); l1 = fmaf(tv.w, a1[q].w, l1);
        }
        out[(size_t)m * OUT_F + n]     = fmaf(s0, sc0, l0 + bs0);
        out[(size_t)m * OUT_F + n + 1] = fmaf(s1, sc1, l1 + bs1);
    }
}

extern "C" void kernel_launch(void* const* d_in, const int* in_sizes, int n_in,
                              void* d_out, int out_size, void* d_ws, size_t ws_size,
                              hipStream_t stream) {
    const float* x      = (const float*)d_in[0];
    const int*   wp     = (const int*)d_in[1];   // uint8 input -> int32 on device
    const float* scale  = (const float*)d_in[2];
    const float* lora_A = (const float*)d_in[3];
    const float* lora_B = (const float*)d_in[4];
    const float* bias   = (const float*)d_in[5];
    float* out = (float*)d_out;

    char* ws = (char*)d_ws;
    unsigned short* xt = (unsigned short*)(ws + XB_OFF);
    float* tB = (float*)(ws + TB_OFF);
    unsigned short* pO = (unsigned short*)(ws + PO_OFF);

    cvt_x<<<512, 256, 0, stream>>>(x, xt);
    lora_t<<<N_TOK * LKC, 256, 0, stream>>>(x, lora_B, tB);
    ternary_gemm<<<2 * (OUT_F / 32) * KSPLIT, 64, 0, stream>>>(xt, wp, pO);
    reduce_out<<<16 * 32, 256, 0, stream>>>(pO, tB, scale, lora_A, bias, out);
}

// Round 20
// 59.428 us; speedup vs baseline: 1.1606x; 1.0528x over previous
//
#include <hip/hip_runtime.h>
#include <hip/hip_bf16.h>
#include <stdint.h>

typedef float f32x4 __attribute__((ext_vector_type(4)));
typedef __bf16 bf16x8 __attribute__((ext_vector_type(8)));
typedef unsigned short ushort8 __attribute__((ext_vector_type(8)));

#define N_TOK 128
#define OUT_F 8192
#define IN_F  8192
#define RANK  32

#define KSPLIT 8                // main-gemm k-split
#define KB    (IN_F / KSPLIT)   // 1024 codes per block
#define BK    64
#define NSTEP (KB / BK)         // 16
#define WSTRIDE 16              // ints per step per W row (BK/4)
#define LKC   4                 // lora-t k-chunks

// workspace layout (bytes)
#define XB_OFF 0
#define TB_OFF ((size_t)N_TOK * IN_F * 2)                      // 2 MiB fragment-ordered bf16 x
#define PO_OFF (TB_OFF + (size_t)LKC * N_TOK * RANK * 4)       // + 64 KiB t-partials
// pO: KSPLIT * 128 * 8192 bf16 = 16 MiB

__device__ __forceinline__ unsigned short bf16r(float f) {
    uint32_t u = __float_as_uint(f);
    return (unsigned short)((u + 0x7FFFu + ((u >> 16) & 1u)) >> 16);
}

__device__ __forceinline__ int swz(int row, int col) { return col ^ ((row & 7) << 3); }

// ---------------- kernel A: x fp32 -> bf16 in MFMA-fragment record order ----------------
// record rec = (sblk*2 + kk)*8 + ar16  (1 KiB each: 64 lanes x 16 B).
// lane l holds X[ar16*16 + (l&15)][sblk*64 + kk*32 + (l>>4)*8 .. +8].
__global__ __launch_bounds__(256) void cvt_x(const float* __restrict__ x,
                                             unsigned short* __restrict__ xt) {
    size_t f = (size_t)blockIdx.x * 256 + threadIdx.x;  // 0..131071 (16-B chunks)
    int lane = (int)(f & 63);
    int rec  = (int)(f >> 6);          // 0..2047
    int ar16 = rec & 7;
    int kk   = (rec >> 3) & 1;
    int sblk = rec >> 4;               // 0..127
    int row = ar16 * 16 + (lane & 15);
    int k   = sblk * 64 + kk * 32 + (lane >> 4) * 8;
    const float4* sp = (const float4*)(x + (size_t)row * IN_F + k);
    float4 a = sp[0], b = sp[1];
    ushort8 o;
    o[0] = bf16r(a.x); o[1] = bf16r(a.y); o[2] = bf16r(a.z); o[3] = bf16r(a.w);
    o[4] = bf16r(b.x); o[5] = bf16r(b.y); o[6] = bf16r(b.z); o[7] = bf16r(b.w);
    *(ushort8*)(xt + f * 8) = o;
}

// ---------------- kernel B: t-partials = x @ lora_B^T, coalesced ----------------
__global__ __launch_bounds__(256) void lora_t(const float* __restrict__ x,
                                              const float* __restrict__ lb,
                                              float* __restrict__ tB) {
    __shared__ float ts[256][33];
    __shared__ float ps[8][32];
    const int m = blockIdx.x >> 2, kc = blockIdx.x & 3;
    const int tid = threadIdx.x;
    const int c0 = kc * 2048 + tid * 8;
    float4 xv0 = *(const float4*)(x + (size_t)m * IN_F + c0);
    float4 xv1 = *(const float4*)(x + (size_t)m * IN_F + c0 + 4);
#pragma unroll
    for (int r = 0; r < RANK; ++r) {
        const float4* bp = (const float4*)(lb + (size_t)r * IN_F + c0);
        float4 b0 = bp[0], b1 = bp[1];
        float s = xv0.x * b0.x + xv0.y * b0.y + xv0.z * b0.z + xv0.w * b0.w +
                  xv1.x * b1.x + xv1.y * b1.y + xv1.z * b1.z + xv1.w * b1.w;
        ts[tid][r] = s;
    }
    __syncthreads();
    {
        int g = tid >> 5, r = tid & 31;
        float s = 0.f;
        for (int j = 0; j < 32; ++j) s += ts[g * 32 + j][r];
        ps[g][r] = s;
    }
    __syncthreads();
    if (tid < 32) {
        float s = 0.f;
#pragma unroll
        for (int g = 0; g < 8; ++g) s += ps[g][tid];
        tB[(kc * N_TOK + m) * RANK + tid] = s;
    }
}

// ---------------- decode: 16 ternary codes (4 widened ints) -> 8 dwords of bf16 pairs ----------------
__device__ __forceinline__ void decodeW(int4 v, uint32_t d[8]) {
    uint32_t p = (uint32_t)v.x | ((uint32_t)v.y << 8) |
                 ((uint32_t)v.z << 16) | ((uint32_t)v.w << 24);
    const uint32_t HI = 0x403F00BFu;
    const uint32_t LO = 0x00800080u;
#pragma unroll
    for (int j = 0; j < 8; ++j) {
        uint32_t c0 = (p >> (4 * j)) & 3u;
        uint32_t c1 = (p >> (4 * j + 2)) & 3u;
        uint32_t t = c0 | (c1 << 16);
        uint32_t sel = (t | (t << 8)) + 0x04000400u;
        d[j] = __builtin_amdgcn_perm(HI, LO, sel);
    }
}

// ---------------- kernel C: ternary GEMM — ROLLED K-loop (I-cache-resident body) ----------
// dbuf ww, one lgkm-only barrier per step; A JIT from L2 fragment records; W reg ring
// with static parity (loop processes 2 steps/iter, #pragma unroll 1 -> ~4 KB body).
// grid = 64 n-tiles * KSPLIT(8) = 512 blocks, 256 threads (4 waves, 2x2 of 64x64).
__global__ __launch_bounds__(256) void ternary_gemm(const unsigned short* __restrict__ xt,
                                                    const int* __restrict__ wp,
                                                    unsigned short* __restrict__ pO) {
    __shared__ unsigned short ww[2][128][64];  // 2 x 16 KiB, XOR-swizzled
    const int tid = threadIdx.x;
    const int nb = blockIdx.x >> 3;
    const int ks = blockIdx.x & 7;
    const int n0 = nb * 128;
    const int lane = tid & 63;
    const int wid = tid >> 6;
    const int wr = wid >> 1, wc = wid & 1;

    const int srow = tid >> 2;
    const int xcol = (tid & 3) * 16;
    const int* pg0 = wp + (size_t)(n0 + srow) * (IN_F / 4) + ks * (KB / 4) + (tid & 3) * 4;
    const int* pg1 = pg0 + (size_t)64 * (IN_F / 4);

    const int arow = lane & 15;
    const int kgrp = (lane >> 4) * 8;
    const int wc0 = swz(srow, xcol), wc1 = swz(srow, xcol + 8);

    // A record base: rec = (ks*NSTEP + s)*16 + kk*8 + ar16; 512 ushorts each
    const unsigned short* abase = xt + ((size_t)(ks * NSTEP) * 16) * 512 + lane * 8;
#define LDA(s_, kk_, ar_) \
    (*(const bf16x8*)(abase + ((size_t)((s_)*16 + (kk_)*8 + (wr * 4 + (ar_)))) * 512))

#define STAGE_WW(wreg0, wreg1, buf_)                                              \
    {                                                                             \
        uint32_t d0[8], d1[8];                                                    \
        decodeW((wreg0), d0);                                                     \
        decodeW((wreg1), d1);                                                     \
        *(uint4*)&ww[(buf_)][srow][wc0]      = make_uint4(d0[0], d0[1], d0[2], d0[3]); \
        *(uint4*)&ww[(buf_)][srow][wc1]      = make_uint4(d0[4], d0[5], d0[6], d0[7]); \
        *(uint4*)&ww[(buf_)][srow + 64][wc0] = make_uint4(d1[0], d1[1], d1[2], d1[3]); \
        *(uint4*)&ww[(buf_)][srow + 64][wc1] = make_uint4(d1[4], d1[5], d1[6], d1[7]); \
    }

#define MFMA_STEP(s_, buf_)                                                       \
    {                                                                             \
        _Pragma("unroll")                                                         \
        for (int kk = 0; kk < 2; ++kk) {                                          \
            bf16x8 aK[4], bfr[4];                                                 \
            _Pragma("unroll")                                                     \
            for (int ar = 0; ar < 4; ++ar) aK[ar] = LDA((s_), kk, ar);            \
            _Pragma("unroll")                                                     \
            for (int br = 0; br < 4; ++br) {                                      \
                int row = wc * 64 + br * 16 + arow;                               \
                bfr[br] = *(const bf16x8*)&ww[(buf_)][row][swz(row, kk * 32 + kgrp)]; \
            }                                                                     \
            _Pragma("unroll")                                                     \
            for (int ar = 0; ar < 4; ++ar)                                        \
                _Pragma("unroll")                                                 \
                for (int br = 0; br < 4; ++br)                                    \
                    acc[ar][br] = __builtin_amdgcn_mfma_f32_16x16x32_bf16(        \
                        aK[ar], bfr[br], acc[ar][br], 0, 0, 0);                   \
        }                                                                         \
    }

#define LGKM_BARRIER                                                              \
    __builtin_amdgcn_sched_barrier(0);                                            \
    asm volatile("s_waitcnt lgkmcnt(0)" ::: "memory");                            \
    __builtin_amdgcn_s_barrier();                                                 \
    __builtin_amdgcn_sched_barrier(0);

    f32x4 acc[4][4];
#pragma unroll
    for (int i = 0; i < 4; ++i)
#pragma unroll
        for (int j = 0; j < 4; ++j) acc[i][j] = (f32x4){0.f, 0.f, 0.f, 0.f};

    int4 w0a, w0b, w1a, w1b;  // parity-0 / parity-1 packed W (static names, no indexing)

    // ---------- prologue: wP0=W(0), wP1=W(1); decode W(0)->ww[0]; wP0=W(2) ----------
    w0a = *(const int4*)(pg0);
    w0b = *(const int4*)(pg1);
    w1a = *(const int4*)(pg0 + WSTRIDE);
    w1b = *(const int4*)(pg1 + WSTRIDE);
    STAGE_WW(w0a, w0b, 0);
    w0a = *(const int4*)(pg0 + 2 * WSTRIDE);
    w0b = *(const int4*)(pg1 + 2 * WSTRIDE);
    LGKM_BARRIER;

    // ---------- main loop: 2 steps/iter, ROLLED (fits L1I) ----------
#pragma unroll 1
    for (int sp = 0; sp < NSTEP / 2; ++sp) {
        const int s0 = 2 * sp, s1 = 2 * sp + 1;
        // even step s0: MFMA ww[0]; decode W(s1)=wP1 -> ww[1]; refill wP1=W(s0+3)
        MFMA_STEP(s0, 0);
        STAGE_WW(w1a, w1b, 1);
        if (s0 + 3 < NSTEP) {
            w1a = *(const int4*)(pg0 + (s0 + 3) * WSTRIDE);
            w1b = *(const int4*)(pg1 + (s0 + 3) * WSTRIDE);
        }
        LGKM_BARRIER;
        // odd step s1: MFMA ww[1]; decode W(s1+1)=wP0 -> ww[0]; refill wP0=W(s1+3)
        MFMA_STEP(s1, 1);
        if (s1 + 1 < NSTEP) {
            STAGE_WW(w0a, w0b, 0);
            if (s1 + 3 < NSTEP) {
                w0a = *(const int4*)(pg0 + (s1 + 3) * WSTRIDE);
                w0b = *(const int4*)(pg1 + (s1 + 3) * WSTRIDE);
            }
            LGKM_BARRIER;
        }
    }
#undef LDA
#undef STAGE_WW
#undef MFMA_STEP
#undef LGKM_BARRIER

    // epilogue: bf16 partial store
    unsigned short* po = pO + ((size_t)ks << 20);
    const int mrow = (lane >> 4) * 4;
#pragma unroll
    for (int ar = 0; ar < 4; ++ar) {
#pragma unroll
        for (int br = 0; br < 4; ++br) {
            int m = wr * 64 + ar * 16 + mrow;
            int n = n0 + wc * 64 + br * 16 + arow;
            unsigned short* pp = po + (size_t)m * OUT_F + n;
#pragma unroll
            for (int j = 0; j < 4; ++j) pp[(size_t)j * OUT_F] = bf16r(acc[ar][br][j]);
        }
    }
}

// ---------------- kernel D: reduce bf16 partials + scale + lora + bias ----------------
// grid = 16 nb * 32 mg = 512 blocks; thread: 2 consecutive n, 4 m's
__global__ __launch_bounds__(256) void reduce_out(const unsigned short* __restrict__ pO,
                                                  const float* __restrict__ tB,
                                                  const float* __restrict__ scale,
                                                  const float* __restrict__ lora_A,
                                                  const float* __restrict__ bias,
                                                  float* __restrict__ out) {
    __shared__ float ts[4][RANK];
    int nb = blockIdx.x & 15, mg = blockIdx.x >> 4;
    int tid = threadIdx.x;
    int m0 = mg * 4;
    if (tid < 128) {
        int i = tid >> 5, r = tid & 31;
        float s = 0.f;
#pragma unroll
        for (int c = 0; c < LKC; ++c) s += tB[(c * N_TOK + m0 + i) * RANK + r];
        ts[i][r] = s;
    }
    __syncthreads();
    int n = nb * 512 + tid * 2;
    float sc0 = scale[n], sc1 = scale[n + 1];
    float bs0 = bias[n], bs1 = bias[n + 1];
    float4 a0[8], a1[8];
    const float4* ap0 = (const float4*)(lora_A + (size_t)n * RANK);
    const float4* ap1 = (const float4*)(lora_A + (size_t)(n + 1) * RANK);
#pragma unroll
    for (int q = 0; q < 8; ++q) { a0[q] = ap0[q]; a1[q] = ap1[q]; }
#pragma unroll
    for (int i = 0; i < 4; ++i) {
        int m = m0 + i;
        const unsigned short* pp = pO + (size_t)m * OUT_F + n;
        float s0 = 0.f, s1 = 0.f;
#pragma unroll
        for (int c = 0; c < KSPLIT; ++c) {
            uint32_t u = *(const uint32_t*)(pp + ((size_t)c << 20));
            s0 += __uint_as_float(u << 16);
            s1 += __uint_as_float(u & 0xFFFF0000u);
        }
        float l0 = 0.f, l1 = 0.f;
#pragma unroll
        for (int q = 0; q < 8; ++q) {
            float4 tv = *(const float4*)&ts[i][q * 4];
            l0 = fmaf(tv.x, a0[q].x, l0); l0 = fmaf(tv.y, a0[q].y, l0);
            l0 = fmaf(tv.z, a0[q].z, l0); l0 = fmaf(tv.w, a0[q].w, l0);
            l1 = fmaf(tv.x, a1[q].x, l1); l1 = fmaf(tv.y, a1[q].y, l1);
            l1 = fmaf(tv.z, a1[q].z, l1); l1 = fmaf(tv.w, a1[q].w, l1);
        }
        out[(size_t)m * OUT_F + n]     = fmaf(s0, sc0, l0 + bs0);
        out[(size_t)m * OUT_F + n + 1] = fmaf(s1, sc1, l1 + bs1);
    }
}

extern "C" void kernel_launch(void* const* d_in, const int* in_sizes, int n_in,
                              void* d_out, int out_size, void* d_ws, size_t ws_size,
                              hipStream_t stream) {
    const float* x      = (const float*)d_in[0];
    const int*   wp     = (const int*)d_in[1];   // uint8 input -> int32 on device
    const float* scale  = (const float*)d_in[2];
    const float* lora_A = (const float*)d_in[3];
    const float* lora_B = (const float*)d_in[4];
    const float* bias   = (const float*)d_in[5];
    float* out = (float*)d_out;

    char* ws = (char*)d_ws;
    unsigned short* xt = (unsigned short*)(ws + XB_OFF);
    float* tB = (float*)(ws + TB_OFF);
    unsigned short* pO = (unsigned short*)(ws + PO_OFF);

    cvt_x<<<512, 256, 0, stream>>>(x, xt);
    lora_t<<<N_TOK * LKC, 256, 0, stream>>>(x, lora_B, tB);
    ternary_gemm<<<(OUT_F / 128) * KSPLIT, 256, 0, stream>>>(xt, wp, pO);
    reduce_out<<<16 * 32, 256, 0, stream>>>(pO, tB, scale, lora_A, bias, out);
}

// Round 21
// 55.789 us; speedup vs baseline: 1.2363x; 1.0652x over previous
//
#include <hip/hip_runtime.h>
#include <hip/hip_bf16.h>
#include <stdint.h>

typedef float f32x4 __attribute__((ext_vector_type(4)));
typedef __bf16 bf16x8 __attribute__((ext_vector_type(8)));
typedef unsigned short ushort8 __attribute__((ext_vector_type(8)));

#define N_TOK 128
#define OUT_F 8192
#define IN_F  8192
#define RANK  32

#define KSPLIT 8                // main-gemm k-split
#define KB    (IN_F / KSPLIT)   // 1024 codes per block
#define BK    64
#define NSTEP (KB / BK)         // 16
#define WSTRIDE 16              // ints per step per W row (BK/4)
#define LKC   4                 // lora-t k-chunks

// workspace layout (bytes)
#define XB_OFF 0
#define TB_OFF ((size_t)N_TOK * IN_F * 2)                      // 2 MiB fragment-ordered bf16 x
#define PO_OFF (TB_OFF + (size_t)LKC * N_TOK * RANK * 4)       // + 64 KiB t-partials
// pO: KSPLIT * 128 * 8192 bf16 = 16 MiB

__device__ __forceinline__ unsigned short bf16r(float f) {
    uint32_t u = __float_as_uint(f);
    return (unsigned short)((u + 0x7FFFu + ((u >> 16) & 1u)) >> 16);
}

__device__ __forceinline__ int swz(int row, int col) { return col ^ ((row & 7) << 3); }

// ---------------- kernel A: x fp32 -> bf16 in MFMA-fragment record order ----------------
// record rec = (sblk*2 + kk)*8 + ar16  (1 KiB each: 64 lanes x 16 B).
// lane l holds X[ar16*16 + (l&15)][sblk*64 + kk*32 + (l>>4)*8 .. +8].
__global__ __launch_bounds__(256) void cvt_x(const float* __restrict__ x,
                                             unsigned short* __restrict__ xt) {
    size_t f = (size_t)blockIdx.x * 256 + threadIdx.x;  // 0..131071 (16-B chunks)
    int lane = (int)(f & 63);
    int rec  = (int)(f >> 6);          // 0..2047
    int ar16 = rec & 7;
    int kk   = (rec >> 3) & 1;
    int sblk = rec >> 4;               // 0..127
    int row = ar16 * 16 + (lane & 15);
    int k   = sblk * 64 + kk * 32 + (lane >> 4) * 8;
    const float4* sp = (const float4*)(x + (size_t)row * IN_F + k);
    float4 a = sp[0], b = sp[1];
    ushort8 o;
    o[0] = bf16r(a.x); o[1] = bf16r(a.y); o[2] = bf16r(a.z); o[3] = bf16r(a.w);
    o[4] = bf16r(b.x); o[5] = bf16r(b.y); o[6] = bf16r(b.z); o[7] = bf16r(b.w);
    *(ushort8*)(xt + f * 8) = o;
}

// ---------------- kernel B: t-partials = x @ lora_B^T, coalesced ----------------
__global__ __launch_bounds__(256) void lora_t(const float* __restrict__ x,
                                              const float* __restrict__ lb,
                                              float* __restrict__ tB) {
    __shared__ float ts[256][33];
    __shared__ float ps[8][32];
    const int m = blockIdx.x >> 2, kc = blockIdx.x & 3;
    const int tid = threadIdx.x;
    const int c0 = kc * 2048 + tid * 8;
    float4 xv0 = *(const float4*)(x + (size_t)m * IN_F + c0);
    float4 xv1 = *(const float4*)(x + (size_t)m * IN_F + c0 + 4);
#pragma unroll
    for (int r = 0; r < RANK; ++r) {
        const float4* bp = (const float4*)(lb + (size_t)r * IN_F + c0);
        float4 b0 = bp[0], b1 = bp[1];
        float s = xv0.x * b0.x + xv0.y * b0.y + xv0.z * b0.z + xv0.w * b0.w +
                  xv1.x * b1.x + xv1.y * b1.y + xv1.z * b1.z + xv1.w * b1.w;
        ts[tid][r] = s;
    }
    __syncthreads();
    {
        int g = tid >> 5, r = tid & 31;
        float s = 0.f;
        for (int j = 0; j < 32; ++j) s += ts[g * 32 + j][r];
        ps[g][r] = s;
    }
    __syncthreads();
    if (tid < 32) {
        float s = 0.f;
#pragma unroll
        for (int g = 0; g < 8; ++g) s += ps[g][tid];
        tB[(kc * N_TOK + m) * RANK + tid] = s;
    }
}

// ---------------- decode: 16 ternary codes (4 widened ints) -> 8 dwords of bf16 pairs ----------------
__device__ __forceinline__ void decodeW(int4 v, uint32_t d[8]) {
    uint32_t p = (uint32_t)v.x | ((uint32_t)v.y << 8) |
                 ((uint32_t)v.z << 16) | ((uint32_t)v.w << 24);
    const uint32_t HI = 0x403F00BFu;
    const uint32_t LO = 0x00800080u;
#pragma unroll
    for (int j = 0; j < 8; ++j) {
        uint32_t c0 = (p >> (4 * j)) & 3u;
        uint32_t c1 = (p >> (4 * j + 2)) & 3u;
        uint32_t t = c0 | (c1 << 16);
        uint32_t sel = (t | (t << 8)) + 0x04000400u;
        d[j] = __builtin_amdgcn_perm(HI, LO, sel);
    }
}

// ---------------- kernel C: ternary GEMM — 4-step W-load BURSTS (DRAM-page batching) ----
// Same data path as r13/r17 (dbuf ww, one lgkm-only barrier/step, A JIT from L2
// fragment records).  Only change: W packed loads issue as 8-load bursts covering
// 4 steps (256 B per row back-to-back) so same-DRAM-page requests batch at the
// memory controller; each burst is issued 4+ steps before first use.
// grid = 64 n-tiles * KSPLIT(8) = 512 blocks, 256 threads (4 waves, 2x2 of 64x64).
__global__ __launch_bounds__(256) void ternary_gemm(const unsigned short* __restrict__ xt,
                                                    const int* __restrict__ wp,
                                                    unsigned short* __restrict__ pO) {
    __shared__ unsigned short ww[2][128][64];  // 2 x 16 KiB, XOR-swizzled
    const int tid = threadIdx.x;
    const int nb = blockIdx.x >> 3;
    const int ks = blockIdx.x & 7;
    const int n0 = nb * 128;
    const int lane = tid & 63;
    const int wid = tid >> 6;
    const int wr = wid >> 1, wc = wid & 1;

    const int srow = tid >> 2;
    const int xcol = (tid & 3) * 16;
    const int* pg0 = wp + (size_t)(n0 + srow) * (IN_F / 4) + ks * (KB / 4) + (tid & 3) * 4;
    const int* pg1 = pg0 + (size_t)64 * (IN_F / 4);

    const int arow = lane & 15;
    const int kgrp = (lane >> 4) * 8;
    const int wc0 = swz(srow, xcol), wc1 = swz(srow, xcol + 8);

    // A record base: rec = (ks*NSTEP + s)*16 + kk*8 + ar16; 512 ushorts each
    const unsigned short* abase = xt + ((size_t)(ks * NSTEP) * 16) * 512 + lane * 8;
#define LDA(s_, kk_, ar_) \
    (*(const bf16x8*)(abase + ((size_t)((s_)*16 + (kk_)*8 + (wr * 4 + (ar_)))) * 512))

    f32x4 acc[4][4];
#pragma unroll
    for (int i = 0; i < 4; ++i)
#pragma unroll
        for (int j = 0; j < 4; ++j) acc[i][j] = (f32x4){0.f, 0.f, 0.f, 0.f};

    // W group buffers: group g = steps 4g..4g+3; even g -> wgA, odd g -> wgB.
    int4 wgA[4][2], wgB[4][2];  // [j][row-half]; indices compile-time after unroll

#define LOAD_GROUP(buf_, g_)                                                      \
    {                                                                             \
        __builtin_amdgcn_sched_barrier(0);                                        \
        _Pragma("unroll")                                                         \
        for (int j = 0; j < 4; ++j) {                                             \
            buf_[j][0] = *(const int4*)(pg0 + ((g_)*4 + j) * WSTRIDE);            \
            buf_[j][1] = *(const int4*)(pg1 + ((g_)*4 + j) * WSTRIDE);            \
        }                                                                         \
        __builtin_amdgcn_sched_barrier(0);                                        \
    }

#define STAGE_WW(w0_, w1_, buf_)                                                  \
    {                                                                             \
        uint32_t d0[8], d1[8];                                                    \
        decodeW((w0_), d0);                                                       \
        decodeW((w1_), d1);                                                       \
        *(uint4*)&ww[(buf_)][srow][wc0]      = make_uint4(d0[0], d0[1], d0[2], d0[3]); \
        *(uint4*)&ww[(buf_)][srow][wc1]      = make_uint4(d0[4], d0[5], d0[6], d0[7]); \
        *(uint4*)&ww[(buf_)][srow + 64][wc0] = make_uint4(d1[0], d1[1], d1[2], d1[3]); \
        *(uint4*)&ww[(buf_)][srow + 64][wc1] = make_uint4(d1[4], d1[5], d1[6], d1[7]); \
    }

#define LGKM_BARRIER                                                              \
    __builtin_amdgcn_sched_barrier(0);                                            \
    asm volatile("s_waitcnt lgkmcnt(0)" ::: "memory");                            \
    __builtin_amdgcn_s_barrier();                                                 \
    __builtin_amdgcn_sched_barrier(0);

    // ---------- prologue: burst-load groups 0,1 (16 loads); decode W(0) -> ww[0] ----------
    LOAD_GROUP(wgA, 0);
    LOAD_GROUP(wgB, 1);
    STAGE_WW(wgA[0][0], wgA[0][1], 0);
    LGKM_BARRIER;

    // ---------- main loop, fully unrolled; one barrier per step ----------
#pragma unroll
    for (int s = 0; s < NSTEP; ++s) {
        const int cur = s & 1, nxt = cur ^ 1;
        // MFMA on ww[cur]; A JIT per kk (L2-resident records)
#pragma unroll
        for (int kk = 0; kk < 2; ++kk) {
            bf16x8 aK[4], bfr[4];
#pragma unroll
            for (int ar = 0; ar < 4; ++ar) aK[ar] = LDA(s, kk, ar);
#pragma unroll
            for (int br = 0; br < 4; ++br) {
                int row = wc * 64 + br * 16 + arow;
                bfr[br] = *(const bf16x8*)&ww[cur][row][swz(row, kk * 32 + kgrp)];
            }
#pragma unroll
            for (int ar = 0; ar < 4; ++ar)
#pragma unroll
                for (int br = 0; br < 4; ++br)
                    acc[ar][br] = __builtin_amdgcn_mfma_f32_16x16x32_bf16(
                        aK[ar], bfr[br], acc[ar][br], 0, 0, 0);
        }
        // end of group g's compute window: burst-load group g+2 into the freed buffer
        if ((s & 3) == 3 && (s >> 2) + 2 < NSTEP / 4) {
            const int gn = (s >> 2) + 2;
            if (gn & 1) { LOAD_GROUP(wgB, gn); }
            else        { LOAD_GROUP(wgA, gn); }
        }
        // decode W(s+1) -> ww[nxt] (group regs loaded >=4 steps ago; counted vmcnt wait)
        if (s + 1 < NSTEP) {
            const int sn = s + 1;
            const int jn = sn & 3;
            if ((sn >> 2) & 1) { STAGE_WW(wgB[jn][0], wgB[jn][1], nxt); }
            else               { STAGE_WW(wgA[jn][0], wgA[jn][1], nxt); }
            LGKM_BARRIER;
        }
    }
#undef LDA
#undef LOAD_GROUP
#undef STAGE_WW
#undef LGKM_BARRIER

    // epilogue: bf16 partial store
    unsigned short* po = pO + ((size_t)ks << 20);
    const int mrow = (lane >> 4) * 4;
#pragma unroll
    for (int ar = 0; ar < 4; ++ar) {
#pragma unroll
        for (int br = 0; br < 4; ++br) {
            int m = wr * 64 + ar * 16 + mrow;
            int n = n0 + wc * 64 + br * 16 + arow;
            unsigned short* pp = po + (size_t)m * OUT_F + n;
#pragma unroll
            for (int j = 0; j < 4; ++j) pp[(size_t)j * OUT_F] = bf16r(acc[ar][br][j]);
        }
    }
}

// ---------------- kernel D: reduce bf16 partials + scale + lora + bias ----------------
// grid = 16 nb * 32 mg = 512 blocks; thread: 2 consecutive n, 4 m's
__global__ __launch_bounds__(256) void reduce_out(const unsigned short* __restrict__ pO,
                                                  const float* __restrict__ tB,
                                                  const float* __restrict__ scale,
                                                  const float* __restrict__ lora_A,
                                                  const float* __restrict__ bias,
                                                  float* __restrict__ out) {
    __shared__ float ts[4][RANK];
    int nb = blockIdx.x & 15, mg = blockIdx.x >> 4;
    int tid = threadIdx.x;
    int m0 = mg * 4;
    if (tid < 128) {
        int i = tid >> 5, r = tid & 31;
        float s = 0.f;
#pragma unroll
        for (int c = 0; c < LKC; ++c) s += tB[(c * N_TOK + m0 + i) * RANK + r];
        ts[i][r] = s;
    }
    __syncthreads();
    int n = nb * 512 + tid * 2;
    float sc0 = scale[n], sc1 = scale[n + 1];
    float bs0 = bias[n], bs1 = bias[n + 1];
    float4 a0[8], a1[8];
    const float4* ap0 = (const float4*)(lora_A + (size_t)n * RANK);
    const float4* ap1 = (const float4*)(lora_A + (size_t)(n + 1) * RANK);
#pragma unroll
    for (int q = 0; q < 8; ++q) { a0[q] = ap0[q]; a1[q] = ap1[q]; }
#pragma unroll
    for (int i = 0; i < 4; ++i) {
        int m = m0 + i;
        const unsigned short* pp = pO + (size_t)m * OUT_F + n;
        float s0 = 0.f, s1 = 0.f;
#pragma unroll
        for (int c = 0; c < KSPLIT; ++c) {
            uint32_t u = *(const uint32_t*)(pp + ((size_t)c << 20));
            s0 += __uint_as_float(u << 16);
            s1 += __uint_as_float(u & 0xFFFF0000u);
        }
        float l0 = 0.f, l1 = 0.f;
#pragma unroll
        for (int q = 0; q < 8; ++q) {
            float4 tv = *(const float4*)&ts[i][q * 4];
            l0 = fmaf(tv.x, a0[q].x, l0); l0 = fmaf(tv.y, a0[q].y, l0);
            l0 = fmaf(tv.z, a0[q].z, l0); l0 = fmaf(tv.w, a0[q].w, l0);
            l1 = fmaf(tv.x, a1[q].x, l1); l1 = fmaf(tv.y, a1[q].y, l1);
            l1 = fmaf(tv.z, a1[q].z, l1); l1 = fmaf(tv.w, a1[q].w, l1);
        }
        out[(size_t)m * OUT_F + n]     = fmaf(s0, sc0, l0 + bs0);
        out[(size_t)m * OUT_F + n + 1] = fmaf(s1, sc1, l1 + bs1);
    }
}

extern "C" void kernel_launch(void* const* d_in, const int* in_sizes, int n_in,
                              void* d_out, int out_size, void* d_ws, size_t ws_size,
                              hipStream_t stream) {
    const float* x      = (const float*)d_in[0];
    const int*   wp     = (const int*)d_in[1];   // uint8 input -> int32 on device
    const float* scale  = (const float*)d_in[2];
    const float* lora_A = (const float*)d_in[3];
    const float* lora_B = (const float*)d_in[4];
    const float* bias   = (const float*)d_in[5];
    float* out = (float*)d_out;

    char* ws = (char*)d_ws;
    unsigned short* xt = (unsigned short*)(ws + XB_OFF);
    float* tB = (float*)(ws + TB_OFF);
    unsigned short* pO = (unsigned short*)(ws + PO_OFF);

    cvt_x<<<512, 256, 0, stream>>>(x, xt);
    lora_t<<<N_TOK * LKC, 256, 0, stream>>>(x, lora_B, tB);
    ternary_gemm<<<(OUT_F / 128) * KSPLIT, 256, 0, stream>>>(xt, wp, pO);
    reduce_out<<<16 * 32, 256, 0, stream>>>(pO, tB, scale, lora_A, bias, out);
}